// Round 5
// baseline (120.164 us; speedup 1.0000x reference)
//
#include <hip/hip_runtime.h>
#include <math.h>

// Ising-flip kernel, round 2: float4 vectorization (4 px/thread) + full load
// prefetch for ILP. Numerics identical to round 1 (absmax 0.0):
//   sc: sequential channel sum c=0..7
//   Js: center, y-1, y+1, x-1, x+1, y-2, y+2, x-2, x+2 (left-assoc adds)
//   de = (2*s)*Js ; arg = (-de)*b ; p = (float)exp((double)arg) if de>0 else 1
//   out = ((rand < p) && dropout>0.5) ? -s : s ; channel 8 = b passthrough

#define NB 4
#define NC 8
#define HH 1024
#define WW 1024
#define PIX (HH * WW)

__device__ __forceinline__ float g4(const float4& v, int i) {
    return i == 0 ? v.x : i == 1 ? v.y : i == 2 ? v.z : v.w;
}
__device__ __forceinline__ void s4(float4& v, int i, float f) {
    if (i == 0) v.x = f; else if (i == 1) v.y = f; else if (i == 2) v.z = f; else v.w = f;
}

__global__ __launch_bounds__(256) void sc_kernel(const float* __restrict__ x,
                                                 float* __restrict__ sc) {
    int tid = blockIdx.x * 256 + threadIdx.x;        // 0 .. NB*PIX/4-1
    int n   = tid >> 18;
    int g   = tid & ((PIX / 4) - 1);
    const float* base = x + (size_t)n * 9 * PIX + (size_t)g * 4;
    float4 s = *reinterpret_cast<const float4*>(base);
#pragma unroll
    for (int c = 1; c < NC; ++c) {
        float4 t = *reinterpret_cast<const float4*>(base + (size_t)c * PIX);
        s.x += t.x; s.y += t.y; s.z += t.z; s.w += t.w;
    }
    *reinterpret_cast<float4*>(sc + (size_t)n * PIX + (size_t)g * 4) = s;
}

__global__ __launch_bounds__(256) void ising_kernel(const float* __restrict__ x,
                                                    const float* __restrict__ rnd,
                                                    const float* __restrict__ dr,
                                                    const float* __restrict__ sc,
                                                    float* __restrict__ out) {
    int tid  = blockIdx.x * 256 + threadIdx.x;
    int n    = tid >> 18;
    int g    = tid & ((PIX / 4) - 1);
    int pix0 = g << 2;                                // multiple of 4
    int y    = pix0 >> 10;
    int xc   = pix0 & (WW - 1);

    const float* scn = sc + (size_t)n * PIX;
    int ym1 = (y - 1) & (HH - 1), yp1 = (y + 1) & (HH - 1);
    int ym2 = (y - 2) & (HH - 1), yp2 = (y + 2) & (HH - 1);
    int xA  = (xc - 4) & (WW - 1);                    // aligned left neighbor quad
    int xCq = (xc + 4) & (WW - 1);                    // aligned right neighbor quad

    // ---- issue ALL loads up front (independent -> deep in flight) ----
    const float* xs = x   + (size_t)n * 9  * PIX + pix0;
    const float* rs = rnd + (size_t)n * NC * PIX + pix0;

    float4 sv[NC], rv[NC];
#pragma unroll
    for (int c = 0; c < NC; ++c)
        sv[c] = *reinterpret_cast<const float4*>(xs + (size_t)c * PIX);
#pragma unroll
    for (int c = 0; c < NC; ++c)
        rv[c] = *reinterpret_cast<const float4*>(rs + (size_t)c * PIX);
    float4 bv = *reinterpret_cast<const float4*>(xs + (size_t)NC * PIX);
    float4 dv = *reinterpret_cast<const float4*>(dr + pix0);

    float4 rB  = *reinterpret_cast<const float4*>(scn + (y   << 10) + xc);
    float4 rA  = *reinterpret_cast<const float4*>(scn + (y   << 10) + xA);
    float4 rC  = *reinterpret_cast<const float4*>(scn + (y   << 10) + xCq);
    float4 rM1 = *reinterpret_cast<const float4*>(scn + (ym1 << 10) + xc);
    float4 rP1 = *reinterpret_cast<const float4*>(scn + (yp1 << 10) + xc);
    float4 rM2 = *reinterpret_cast<const float4*>(scn + (ym2 << 10) + xc);
    float4 rP2 = *reinterpret_cast<const float4*>(scn + (yp2 << 10) + xc);

    // ---- Js per pixel, exact reference add order ----
    float Js[4];
#pragma unroll
    for (int i = 0; i < 4; ++i) {
        float cen = g4(rB, i);
        float vy1m = g4(rM1, i), vy1p = g4(rP1, i);
        float vy2m = g4(rM2, i), vy2p = g4(rP2, i);
        float vx1m = (i == 0) ? g4(rA, 3) : g4(rB, i - 1);
        float vx1p = (i == 3) ? g4(rC, 0) : g4(rB, i + 1);
        float vx2m = (i < 2) ? g4(rA, 2 + i) : g4(rB, i - 2);
        float vx2p = (i < 2) ? g4(rB, i + 2) : g4(rC, i - 2);
        float j = cen;
        j = j + vy1m; j = j + vy1p;
        j = j + vx1m; j = j + vx1p;
        j = j + vy2m; j = j + vy2p;
        j = j + vx2m; j = j + vx2p;
        Js[i] = j;
    }

    bool dm[4];
#pragma unroll
    for (int i = 0; i < 4; ++i) dm[i] = g4(dv, i) > 0.5f;

    float* os = out + (size_t)n * 9 * PIX + pix0;
#pragma unroll
    for (int c = 0; c < NC; ++c) {
        float4 o;
#pragma unroll
        for (int i = 0; i < 4; ++i) {
            float s = g4(sv[c], i);
            float r = g4(rv[c], i);
            float de = (2.0f * s) * Js[i];
            float p = 1.0f;
            if (de > 0.0f) {
                float arg = (-de) * g4(bv, i);
                p = (float)exp((double)arg);
            }
            bool cond = (r < p) && dm[i];
            s4(o, i, cond ? -s : s);
        }
        *reinterpret_cast<float4*>(os + (size_t)c * PIX) = o;
    }
    *reinterpret_cast<float4*>(os + (size_t)NC * PIX) = bv;
}

extern "C" void kernel_launch(void* const* d_in, const int* in_sizes, int n_in,
                              void* d_out, int out_size, void* d_ws, size_t ws_size,
                              hipStream_t stream) {
    const float* x   = (const float*)d_in[0];
    const float* rnd = (const float*)d_in[1];
    const float* dr  = (const float*)d_in[2];
    float* out = (float*)d_out;
    float* sc  = (float*)d_ws;                        // NB*PIX*4 = 16 MiB

    const int blocks = NB * PIX / 4 / 256;            // 4096
    sc_kernel<<<blocks, 256, 0, stream>>>(x, sc);
    ising_kernel<<<blocks, 256, 0, stream>>>(x, rnd, dr, sc, out);
}

// Round 6
// 115.142 us; speedup vs baseline: 1.0436x; 1.0436x over previous
//
#include <hip/hip_runtime.h>
#include <math.h>

// Ising-flip, round 6: 2 px/thread (float2) + FORCED load materialization via
// empty asm register constraints (round 5 showed the compiler sinks prefetch
// loads otherwise: VGPR=60 < the 64 needed to hold them). Numerics identical
// to the passing rounds (absmax 0.0):
//   sc: sequential channel sum c=0..7
//   Js: center, y-1, y+1, x-1, x+1, y-2, y+2, x-2, x+2 (left-assoc adds)
//   de = (2*s)*Js ; arg = (-de)*b ; p = (float)exp((double)arg) if de>0 else 1
//   out = ((rand < p) && dropout>0.5) ? -s : s ; channel 8 = b passthrough

#define NB 4
#define NC 8
#define HH 1024
#define WW 1024
#define PIX (HH * WW)

#define KEEP2(v) asm volatile("" : "+v"(v.x), "+v"(v.y))
#define KEEP4(v) asm volatile("" : "+v"(v.x), "+v"(v.y), "+v"(v.z), "+v"(v.w))

__global__ __launch_bounds__(256) void sc_kernel(const float* __restrict__ x,
                                                 float* __restrict__ sc) {
    int tid = blockIdx.x * 256 + threadIdx.x;        // 0 .. NB*PIX/4-1
    int n   = tid >> 18;
    int g   = tid & ((PIX / 4) - 1);
    const float* base = x + (size_t)n * 9 * PIX + (size_t)g * 4;
    float4 t[NC];
#pragma unroll
    for (int c = 0; c < NC; ++c)
        t[c] = *reinterpret_cast<const float4*>(base + (size_t)c * PIX);
#pragma unroll
    for (int c = 0; c < NC; ++c) KEEP4(t[c]);        // all 8 loads in flight
    float4 s = t[0];
#pragma unroll
    for (int c = 1; c < NC; ++c) {
        s.x += t[c].x; s.y += t[c].y; s.z += t[c].z; s.w += t[c].w;
    }
    *reinterpret_cast<float4*>(sc + (size_t)n * PIX + (size_t)g * 4) = s;
}

__global__ __launch_bounds__(256) void ising_kernel(const float* __restrict__ x,
                                                    const float* __restrict__ rnd,
                                                    const float* __restrict__ dr,
                                                    const float* __restrict__ sc,
                                                    float* __restrict__ out) {
    int tid  = blockIdx.x * 256 + threadIdx.x;       // 0 .. NB*PIX/2-1
    int n    = tid >> 19;
    int g    = tid & ((PIX / 2) - 1);
    int pix0 = g << 1;                               // even pixel index
    int y    = pix0 >> 10;
    int xc   = pix0 & (WW - 1);

    const float* scn = sc + (size_t)n * PIX;
    int ym1 = (y - 1) & (HH - 1), yp1 = (y + 1) & (HH - 1);
    int ym2 = (y - 2) & (HH - 1), yp2 = (y + 2) & (HH - 1);
    int xA  = (xc - 2) & (WW - 1);                   // covers cols xc-2, xc-1
    int xC  = (xc + 2) & (WW - 1);                   // covers cols xc+2, xc+3

    const float* xs = x   + (size_t)n * 9  * PIX + pix0;
    const float* rs = rnd + (size_t)n * NC * PIX + pix0;

    // ---- issue ALL 25 loads ----
    float2 sv[NC], rv[NC];
#pragma unroll
    for (int c = 0; c < NC; ++c)
        sv[c] = *reinterpret_cast<const float2*>(xs + (size_t)c * PIX);
#pragma unroll
    for (int c = 0; c < NC; ++c)
        rv[c] = *reinterpret_cast<const float2*>(rs + (size_t)c * PIX);
    float2 bv = *reinterpret_cast<const float2*>(xs + (size_t)NC * PIX);
    float2 dv = *reinterpret_cast<const float2*>(dr + pix0);

    float2 rB  = *reinterpret_cast<const float2*>(scn + (y   << 10) + xc);
    float2 rA  = *reinterpret_cast<const float2*>(scn + (y   << 10) + xA);
    float2 rC  = *reinterpret_cast<const float2*>(scn + (y   << 10) + xC);
    float2 rM1 = *reinterpret_cast<const float2*>(scn + (ym1 << 10) + xc);
    float2 rP1 = *reinterpret_cast<const float2*>(scn + (yp1 << 10) + xc);
    float2 rM2 = *reinterpret_cast<const float2*>(scn + (ym2 << 10) + xc);
    float2 rP2 = *reinterpret_cast<const float2*>(scn + (yp2 << 10) + xc);

    // ---- register-constraint barrier: loads cannot be sunk past this ----
#pragma unroll
    for (int c = 0; c < NC; ++c) { KEEP2(sv[c]); KEEP2(rv[c]); }
    KEEP2(bv); KEEP2(dv);
    KEEP2(rB); KEEP2(rA); KEEP2(rC);
    KEEP2(rM1); KEEP2(rP1); KEEP2(rM2); KEEP2(rP2);

    // ---- Js per pixel, exact reference add order ----
    float Js[2];
#pragma unroll
    for (int i = 0; i < 2; ++i) {
        float cen  = i ? rB.y  : rB.x;
        float vy1m = i ? rM1.y : rM1.x;
        float vy1p = i ? rP1.y : rP1.x;
        float vy2m = i ? rM2.y : rM2.x;
        float vy2p = i ? rP2.y : rP2.x;
        float vx1m = i ? rB.x  : rA.y;               // col xc+i-1
        float vx1p = i ? rC.x  : rB.y;               // col xc+i+1
        float vx2m = i ? rA.y  : rA.x;               // col xc+i-2
        float vx2p = i ? rC.y  : rC.x;               // col xc+i+2
        float j = cen;
        j = j + vy1m; j = j + vy1p;
        j = j + vx1m; j = j + vx1p;
        j = j + vy2m; j = j + vy2p;
        j = j + vx2m; j = j + vx2p;
        Js[i] = j;
    }

    bool dm0 = dv.x > 0.5f, dm1 = dv.y > 0.5f;

    float* os = out + (size_t)n * 9 * PIX + pix0;
#pragma unroll
    for (int c = 0; c < NC; ++c) {
        float2 o;
        {
            float s = sv[c].x, r = rv[c].x;
            float de = (2.0f * s) * Js[0];
            float p = 1.0f;
            if (de > 0.0f) {
                float arg = (-de) * bv.x;
                p = (float)exp((double)arg);
            }
            o.x = ((r < p) && dm0) ? -s : s;
        }
        {
            float s = sv[c].y, r = rv[c].y;
            float de = (2.0f * s) * Js[1];
            float p = 1.0f;
            if (de > 0.0f) {
                float arg = (-de) * bv.y;
                p = (float)exp((double)arg);
            }
            o.y = ((r < p) && dm1) ? -s : s;
        }
        *reinterpret_cast<float2*>(os + (size_t)c * PIX) = o;
    }
    *reinterpret_cast<float2*>(os + (size_t)NC * PIX) = bv;
}

extern "C" void kernel_launch(void* const* d_in, const int* in_sizes, int n_in,
                              void* d_out, int out_size, void* d_ws, size_t ws_size,
                              hipStream_t stream) {
    const float* x   = (const float*)d_in[0];
    const float* rnd = (const float*)d_in[1];
    const float* dr  = (const float*)d_in[2];
    float* out = (float*)d_out;
    float* sc  = (float*)d_ws;                        // NB*PIX*4 = 16 MiB

    sc_kernel<<<NB * PIX / 4 / 256, 256, 0, stream>>>(x, sc);
    ising_kernel<<<NB * PIX / 2 / 256, 256, 0, stream>>>(x, rnd, dr, sc, out);
}